// Round 2
// baseline (902.015 us; speedup 1.0000x reference)
//
#include <hip/hip_runtime.h>

typedef __attribute__((ext_vector_type(8))) _Float16 f16x8;
typedef __attribute__((ext_vector_type(4))) _Float16 f16x4;
typedef __attribute__((ext_vector_type(4))) float f32x4;

#define NB 4
#define NS 4096
#define NE 512

__device__ __forceinline__ f16x8 cvt2(float4 a, float4 b) {
    f16x8 r;
    r[0] = (_Float16)a.x; r[1] = (_Float16)a.y; r[2] = (_Float16)a.z; r[3] = (_Float16)a.w;
    r[4] = (_Float16)b.x; r[5] = (_Float16)b.y; r[6] = (_Float16)b.z; r[7] = (_Float16)b.w;
    return r;
}
__device__ __forceinline__ void gload_lds16(const void* g, void* l) {
    __builtin_amdgcn_global_load_lds(
        (const __attribute__((address_space(1))) void*)g,
        (__attribute__((address_space(3))) void*)l, 16, 0, 0);
}

// ---------------- Stage 1: fused QKV projection (fp32 in, f16 out) ------
// q: natural [row][e]. k: swizzled rows — element (s,e) at s*512 + ((e/8)^(s&7))*8 + e%8.
// v: 32-key chunks with XOR chunk swizzle:
//    element (s,d) at ((bat*128 + ((s&4095)>>5))*512 + d)*32
//                    + ((((s&31)>>3) ^ ((d>>1)&3))<<3) + (s&7)
__global__ __launch_bounds__(256) void proj_kernel(
    const float* __restrict__ Xq, const float* __restrict__ Xk,
    const float* __restrict__ Xv,
    const float* __restrict__ Wq, const float* __restrict__ Wk,
    const float* __restrict__ Wv,
    const float* __restrict__ bq, const float* __restrict__ bk,
    const float* __restrict__ bv,
    _Float16* __restrict__ oq, _Float16* __restrict__ ok,
    _Float16* __restrict__ ovt, int b0)
{
    __shared__ __align__(16) _Float16 As[128 * 32];
    __shared__ __align__(16) _Float16 Bs[128 * 32];
    const int t = threadIdx.x;
    const int w = t >> 6, ln = t & 63;
    const int which = blockIdx.y;
    const float* X    = (which == 0) ? Xq : ((which == 1) ? Xk : Xv);
    const float* W    = (which == 0) ? Wq : ((which == 1) ? Wk : Wv);
    const float* bias = (which == 0) ? bq : ((which == 1) ? bk : bv);

    const int m0 = (blockIdx.x >> 2) * 128;
    const int n0 = (blockIdx.x & 3) * 128;

    const int srow  = t >> 1;
    const int shalf = (t & 1) * 16;
    const float* gA = X + ((size_t)b0 * NS + m0 + srow) * NE + shalf;
    const float* gB = W + (size_t)(n0 + srow) * NE + shalf;
    _Float16* lA = &As[srow * 32 + shalf];
    _Float16* lB = &Bs[srow * 32 + shalf];

    f32x4 acc[4][4] = {};
    const int wm = (w >> 1) * 64, wn = (w & 1) * 64;
    const int lcol = ln & 15, lq = ln >> 4;

    for (int k0 = 0; k0 < NE; k0 += 32) {
        float4 xa0 = *(const float4*)(gA + k0);
        float4 xa1 = *(const float4*)(gA + k0 + 4);
        float4 xa2 = *(const float4*)(gA + k0 + 8);
        float4 xa3 = *(const float4*)(gA + k0 + 12);
        float4 xb0 = *(const float4*)(gB + k0);
        float4 xb1 = *(const float4*)(gB + k0 + 4);
        float4 xb2 = *(const float4*)(gB + k0 + 8);
        float4 xb3 = *(const float4*)(gB + k0 + 12);
        __syncthreads();
        *(f16x8*)lA       = cvt2(xa0, xa1);
        *(f16x8*)(lA + 8) = cvt2(xa2, xa3);
        *(f16x8*)lB       = cvt2(xb0, xb1);
        *(f16x8*)(lB + 8) = cvt2(xb2, xb3);
        __syncthreads();
        f16x8 a[4], b[4];
#pragma unroll
        for (int i = 0; i < 4; i++)
            a[i] = *(const f16x8*)&As[(wm + i * 16 + lcol) * 32 + lq * 8];
#pragma unroll
        for (int j = 0; j < 4; j++)
            b[j] = *(const f16x8*)&Bs[(wn + j * 16 + lcol) * 32 + lq * 8];
#pragma unroll
        for (int i = 0; i < 4; i++)
#pragma unroll
            for (int j = 0; j < 4; j++)
                acc[i][j] = __builtin_amdgcn_mfma_f32_16x16x32_f16(a[i], b[j], acc[i][j], 0, 0, 0);
    }

    // C/D layout: col = lane&15, row = (lane>>4)*4 + reg
    if (which == 0) {
#pragma unroll
        for (int j = 0; j < 4; j++) {
            const int col = n0 + wn + j * 16 + lcol;
            const float bb = bias[col];
#pragma unroll
            for (int i = 0; i < 4; i++) {
                const int rbase = m0 + wm + i * 16 + lq * 4;
#pragma unroll
                for (int r = 0; r < 4; r++)
                    oq[(size_t)(rbase + r) * NE + col] = (_Float16)(acc[i][j][r] + bb);
            }
        }
    } else if (which == 1) {
#pragma unroll
        for (int j = 0; j < 4; j++) {
            const int col = n0 + wn + j * 16 + lcol;
            const int cch = col >> 3, clo = col & 7;
            const float bb = bias[col];
#pragma unroll
            for (int i = 0; i < 4; i++) {
                const int rbase = m0 + wm + i * 16 + lq * 4;
#pragma unroll
                for (int r = 0; r < 4; r++) {
                    const int s = rbase + r;
                    ok[(size_t)s * NE + ((cch ^ (s & 7)) << 3) + clo] =
                        (_Float16)(acc[i][j][r] + bb);
                }
            }
        }
    } else {
#pragma unroll
        for (int j = 0; j < 4; j++) {
            const int d = n0 + wn + j * 16 + lcol;
            const int dsw = (d >> 1) & 3;
            const float bb = bias[d];
#pragma unroll
            for (int i = 0; i < 4; i++) {
                const int rbase = m0 + wm + i * 16 + lq * 4;
                const int bat = rbase >> 12;
                const int sl  = rbase & 4095;
                const int ch  = ((sl >> 3) & 3) ^ dsw;
                f16x4 pk;
#pragma unroll
                for (int r = 0; r < 4; r++) pk[r] = (_Float16)(acc[i][j][r] + bb);
                *(f16x4*)&ovt[(((size_t)bat * 128 + (sl >> 5)) * NE + d) * 32
                              + (ch << 3) + (sl & 7)] = pk;
            }
        }
    }
}

// ---------------- Stage 2: flash attention v7 (split-K, 2 blocks/CU) ----
// 512 thr = 8 waves; block owns 64 q-rows x 2048 keys (one half), KB=32,
// single-buffered drain loop; TLP from the co-resident block hides stalls.
// wave w: rt=w&3 (16 rows); g=w>>2: QK keys [g*16,g*16+16), PV E-half
// [g*256,g*256+256). Writes UNNORMALIZED O + (m,l) partials; combine pass
// merges the two key-halves.
__global__ __launch_bounds__(512, 4) void attn_kernel(
    const _Float16* __restrict__ q, const _Float16* __restrict__ ksw,
    const _Float16* __restrict__ vsw, float* __restrict__ po,
    float* __restrict__ pml, int b0)
{
    __shared__ __align__(16) _Float16 Kb[32 * 512];
    __shared__ __align__(16) _Float16 Vb[512 * 32];
    __shared__ __align__(16) _Float16 Pb[64 * 40];
    __shared__ float mpart[2][64];
    __shared__ float lpart[2][64];

    const int t = threadIdx.x, w = t >> 6, ln = t & 63;
    const int lcol = ln & 15, lq = ln >> 4;
    const int rt = w & 3, g = w >> 2;
    const int xm = lcol & 7;

    // XCD swizzle: each XCD owns one (batch, key-half) -> 4 MiB = one L2
    int qx, half, rel;
    if (gridDim.x == 128 && gridDim.y == 4) {
        const int id = blockIdx.x + (blockIdx.y << 7);   // 0..511, hw xcd = id&7
        rel  = (id & 7) >> 1;
        half = id & 1;
        qx   = id >> 3;
    } else { qx = blockIdx.x & 63; half = blockIdx.x >> 6; rel = blockIdx.y; }
    const int q0 = qx * 64;

    const _Float16* qp = q + ((size_t)rel * NS + q0 + rt * 16 + lcol) * NE + lq * 8;
    f16x8 qf[16];
#pragma unroll
    for (int ks = 0; ks < 16; ks++) qf[ks] = *(const f16x8*)(qp + ks * 32);

    const _Float16* kbase = ksw + (size_t)rel * NS * NE;
    const _Float16* vbase = vsw + (size_t)rel * NS * NE;

    f32x4 oacc[16] = {};
    float m_st[4] = {-1e30f, -1e30f, -1e30f, -1e30f};
    float l_st[4] = {0.f, 0.f, 0.f, 0.f};

    for (int kc = 0; kc < 64; kc++) {
        const int kct = half * 64 + kc;
        __syncthreads();                                 // B0: prev reads done
        const _Float16* ks_src = kbase + (size_t)kct * 32 * NE;
        const _Float16* vs_src = vbase + (size_t)kct * NE * 32;
#pragma unroll
        for (int i = 0; i < 4; i++) {
            const int blk = i * 8 + w;                   // 1 KB block index
            gload_lds16(ks_src + blk * 512 + ln * 8, (_Float16*)Kb + blk * 512);
            gload_lds16(vs_src + blk * 512 + ln * 8, (_Float16*)Vb + blk * 512);
        }
        __syncthreads();                                 // B1: staging visible

        // ---- QK^T: 16 q-rows x 16 keys (keys g*16..+16), K=512
        f32x4 s = {};
        __builtin_amdgcn_s_setprio(1);
#pragma unroll
        for (int ks = 0; ks < 16; ks++) {
            f16x8 kb = *(const f16x8*)&Kb[(g * 16 + lcol) * 512 + ((ks * 4 + lq) ^ xm) * 8];
            s = __builtin_amdgcn_mfma_f32_16x16x32_f16(qf[ks], kb, s, 0, 0, 0);
        }
        __builtin_amdgcn_s_setprio(0);

        // ---- wave-local softmax partials (row=lq*4+r, key=g*16+lcol)
        float pe[4], Mg[4];
#pragma unroll
        for (int r = 0; r < 4; r++) {
            float mx = s[r];
#pragma unroll
            for (int msk = 8; msk; msk >>= 1) mx = fmaxf(mx, __shfl_xor(mx, msk, 64));
            Mg[r] = fmaxf(m_st[r], mx);
            pe[r] = __expf(s[r] - Mg[r]);
            Pb[(rt * 16 + lq * 4 + r) * 40 + g * 16 + lcol] = (_Float16)pe[r];
        }
#pragma unroll
        for (int r = 0; r < 4; r++) {
            float ls = pe[r];
#pragma unroll
            for (int msk = 8; msk; msk >>= 1) ls += __shfl_xor(ls, msk, 64);
            if (lcol == 0) {
                mpart[g][rt * 16 + lq * 4 + r] = Mg[r];
                lpart[g][rt * 16 + lq * 4 + r] = ls;
            }
        }
        __syncthreads();                                 // B2: partials visible

        // ---- combine partials; update running state (state rows)
        float alpha[4];
#pragma unroll
        for (int r = 0; r < 4; r++) {
            const int row = rt * 16 + lq * 4 + r;
            const float M0 = mpart[0][row], M1 = mpart[1][row];
            const float mn = fmaxf(M0, M1);
            alpha[r] = __expf(m_st[r] - mn);
            l_st[r] = l_st[r] * alpha[r]
                    + __expf(M0 - mn) * lpart[0][row]
                    + __expf(M1 - mn) * lpart[1][row];
            m_st[r] = mn;
        }
        const bool allone = (alpha[0] == 1.f) & (alpha[1] == 1.f) &
                            (alpha[2] == 1.f) & (alpha[3] == 1.f);
        if (!__all(allone)) {
#pragma unroll
            for (int et = 0; et < 16; et++) {
                oacc[et][0] *= alpha[0]; oacc[et][1] *= alpha[1];
                oacc[et][2] *= alpha[2]; oacc[et][3] *= alpha[3];
            }
        }

        // ---- P A-fragment (rows = lcol): per-half correction exp(Mg - mn)
        const int frow = rt * 16 + lcol;
        const float F0 = mpart[0][frow], F1 = mpart[1][frow];
        const float fm = fmaxf(F0, F1);
        const _Float16 cf = (_Float16)__expf(((lq < 2) ? F0 : F1) - fm);
        f16x8 pa = *(const f16x8*)&Pb[frow * 40 + lq * 8];
#pragma unroll
        for (int j = 0; j < 8; j++) pa[j] *= cf;

        // ---- PV: rows rt*16..+16, E-cols g*256..+256, K=32
        __builtin_amdgcn_s_setprio(1);
#pragma unroll
        for (int et = 0; et < 16; et++) {
            const int e = g * 256 + et * 16 + lcol;
            const int ch = lq ^ ((e >> 1) & 3);
            f16x8 vf = *(const f16x8*)&Vb[e * 32 + ch * 8];
            oacc[et] = __builtin_amdgcn_mfma_f32_16x16x32_f16(pa, vf, oacc[et], 0, 0, 0);
        }
        __builtin_amdgcn_s_setprio(0);
    }

    // ---- write unnormalized partials: po[(rel*2+half)][row][e], m/l
    const size_t pb = ((size_t)(rel * 2 + half) * NS + q0) * NE;
#pragma unroll
    for (int r = 0; r < 4; r++) {
        const int row = rt * 16 + lq * 4 + r;
        const size_t ob = pb + (size_t)row * NE + g * 256 + lcol;
#pragma unroll
        for (int et = 0; et < 16; et++)
            po[ob + et * 16] = oacc[et][r];
        if (lcol == 0 && g == 0) {
            pml[((size_t)(rel * 2 + half) * 2 + 0) * NS + q0 + row] = m_st[r];
            pml[((size_t)(rel * 2 + half) * 2 + 1) * NS + q0 + row] = l_st[r];
        }
    }
}

// ---------------- Stage 3: combine the two key-halves -------------------
__global__ __launch_bounds__(256) void combine_kernel(
    const float* __restrict__ po, const float* __restrict__ pml,
    float* __restrict__ out, int b0)
{
    const int s = blockIdx.x, rel = blockIdx.y;
    const int e0 = threadIdx.x * 2;
    const float m0 = pml[((size_t)(rel * 2 + 0) * 2 + 0) * NS + s];
    const float l0 = pml[((size_t)(rel * 2 + 0) * 2 + 1) * NS + s];
    const float m1 = pml[((size_t)(rel * 2 + 1) * 2 + 0) * NS + s];
    const float l1 = pml[((size_t)(rel * 2 + 1) * 2 + 1) * NS + s];
    const float mm = fmaxf(m0, m1);
    const float w0 = __expf(m0 - mm), w1 = __expf(m1 - mm);
    const float inv = 1.0f / (l0 * w0 + l1 * w1);
    const size_t r0 = ((size_t)(rel * 2 + 0) * NS + s) * NE + e0;
    const size_t r1 = ((size_t)(rel * 2 + 1) * NS + s) * NE + e0;
    const float2 a = *(const float2*)&po[r0];
    const float2 b = *(const float2*)&po[r1];
    float2 o;
    o.x = (a.x * w0 + b.x * w1) * inv;
    o.y = (a.y * w0 + b.y * w1) * inv;
    *(float2*)&out[((size_t)(b0 + rel) * NS + s) * NE + e0] = o;
}

extern "C" void kernel_launch(void* const* d_in, const int* in_sizes, int n_in,
                              void* d_out, int out_size, void* d_ws, size_t ws_size,
                              hipStream_t stream) {
    const float* query = (const float*)d_in[0];
    const float* key_  = (const float*)d_in[1];
    const float* value = (const float*)d_in[2];
    const float* Wq    = (const float*)d_in[3];
    const float* bq    = (const float*)d_in[4];
    const float* Wk    = (const float*)d_in[5];
    const float* bk    = (const float*)d_in[6];
    const float* Wv    = (const float*)d_in[7];
    const float* bv    = (const float*)d_in[8];

    // per batch: qkv f16 (12 MiB) + O partials f32 (16 MiB) + m/l (64 KiB)
    const size_t per_batch = (size_t)3 * NS * NE * 2
                           + (size_t)2 * NS * NE * 4
                           + (size_t)2 * 2 * NS * 4;
    int nb_chunk = (int)(ws_size / per_batch);
    if (nb_chunk > NB) nb_chunk = NB;
    if (nb_chunk < 1)  nb_chunk = 1;

    _Float16* qh  = (_Float16*)d_ws;
    _Float16* kh  = qh + (size_t)nb_chunk * NS * NE;
    _Float16* vth = kh + (size_t)nb_chunk * NS * NE;
    float*    po  = (float*)(vth + (size_t)nb_chunk * NS * NE);
    float*    pml = po + (size_t)nb_chunk * 2 * NS * NE;

    for (int b0 = 0; b0 < NB; b0 += nb_chunk) {
        int nb = NB - b0 < nb_chunk ? NB - b0 : nb_chunk;
        proj_kernel<<<dim3(nb * 128, 3, 1), 256, 0, stream>>>(
            query, key_, value, Wq, Wk, Wv, bq, bk, bv, qh, kh, vth, b0);
        attn_kernel<<<dim3(128, nb, 1), 512, 0, stream>>>(
            qh, kh, vth, po, pml, b0);
        combine_kernel<<<dim3(NS, nb, 1), 256, 0, stream>>>(
            po, pml, (float*)d_out, b0);
    }
}

// Round 3
// 529.314 us; speedup vs baseline: 1.7041x; 1.7041x over previous
//
#include <hip/hip_runtime.h>

typedef __attribute__((ext_vector_type(8))) _Float16 f16x8;
typedef __attribute__((ext_vector_type(4))) _Float16 f16x4;
typedef __attribute__((ext_vector_type(4))) float f32x4;

#define NB 4
#define NS 4096
#define NE 512

__device__ __forceinline__ f16x8 cvt2(float4 a, float4 b) {
    f16x8 r;
    r[0] = (_Float16)a.x; r[1] = (_Float16)a.y; r[2] = (_Float16)a.z; r[3] = (_Float16)a.w;
    r[4] = (_Float16)b.x; r[5] = (_Float16)b.y; r[6] = (_Float16)b.z; r[7] = (_Float16)b.w;
    return r;
}
__device__ __forceinline__ void gload_lds16(const void* g, void* l) {
    __builtin_amdgcn_global_load_lds(
        (const __attribute__((address_space(1))) void*)g,
        (__attribute__((address_space(3))) void*)l, 16, 0, 0);
}

// ---------------- Stage 1: fused QKV projection (fp32 in, f16 out) ------
// q: natural [row][e]. k: swizzled rows — element (s,e) at s*512 + ((e/8)^(s&7))*8 + e%8.
// v: chunked+swizzled [b][kc][e][64]: (d,s) at ((b*64+kc)*512+d)*64 + (((s&63)/8)^(d&7))*8 + s%8.
__global__ __launch_bounds__(256) void proj_kernel(
    const float* __restrict__ Xq, const float* __restrict__ Xk,
    const float* __restrict__ Xv,
    const float* __restrict__ Wq, const float* __restrict__ Wk,
    const float* __restrict__ Wv,
    const float* __restrict__ bq, const float* __restrict__ bk,
    const float* __restrict__ bv,
    _Float16* __restrict__ oq, _Float16* __restrict__ ok,
    _Float16* __restrict__ ovt, int b0)
{
    __shared__ __align__(16) _Float16 As[128 * 32];
    __shared__ __align__(16) _Float16 Bs[128 * 32];
    const int t = threadIdx.x;
    const int w = t >> 6, ln = t & 63;
    const int which = blockIdx.y;
    const float* X    = (which == 0) ? Xq : ((which == 1) ? Xk : Xv);
    const float* W    = (which == 0) ? Wq : ((which == 1) ? Wk : Wv);
    const float* bias = (which == 0) ? bq : ((which == 1) ? bk : bv);

    const int m0 = (blockIdx.x >> 2) * 128;
    const int n0 = (blockIdx.x & 3) * 128;

    const int srow  = t >> 1;
    const int shalf = (t & 1) * 16;
    const float* gA = X + ((size_t)b0 * NS + m0 + srow) * NE + shalf;
    const float* gB = W + (size_t)(n0 + srow) * NE + shalf;
    _Float16* lA = &As[srow * 32 + shalf];
    _Float16* lB = &Bs[srow * 32 + shalf];

    f32x4 acc[4][4] = {};
    const int wm = (w >> 1) * 64, wn = (w & 1) * 64;
    const int lcol = ln & 15, lq = ln >> 4;

    for (int k0 = 0; k0 < NE; k0 += 32) {
        float4 xa0 = *(const float4*)(gA + k0);
        float4 xa1 = *(const float4*)(gA + k0 + 4);
        float4 xa2 = *(const float4*)(gA + k0 + 8);
        float4 xa3 = *(const float4*)(gA + k0 + 12);
        float4 xb0 = *(const float4*)(gB + k0);
        float4 xb1 = *(const float4*)(gB + k0 + 4);
        float4 xb2 = *(const float4*)(gB + k0 + 8);
        float4 xb3 = *(const float4*)(gB + k0 + 12);
        __syncthreads();
        *(f16x8*)lA       = cvt2(xa0, xa1);
        *(f16x8*)(lA + 8) = cvt2(xa2, xa3);
        *(f16x8*)lB       = cvt2(xb0, xb1);
        *(f16x8*)(lB + 8) = cvt2(xb2, xb3);
        __syncthreads();
        f16x8 a[4], b[4];
#pragma unroll
        for (int i = 0; i < 4; i++)
            a[i] = *(const f16x8*)&As[(wm + i * 16 + lcol) * 32 + lq * 8];
#pragma unroll
        for (int j = 0; j < 4; j++)
            b[j] = *(const f16x8*)&Bs[(wn + j * 16 + lcol) * 32 + lq * 8];
#pragma unroll
        for (int i = 0; i < 4; i++)
#pragma unroll
            for (int j = 0; j < 4; j++)
                acc[i][j] = __builtin_amdgcn_mfma_f32_16x16x32_f16(a[i], b[j], acc[i][j], 0, 0, 0);
    }

    // C/D layout: col = lane&15, row = (lane>>4)*4 + reg
    if (which == 0) {
#pragma unroll
        for (int j = 0; j < 4; j++) {
            const int col = n0 + wn + j * 16 + lcol;
            const float bb = bias[col];
#pragma unroll
            for (int i = 0; i < 4; i++) {
                const int rbase = m0 + wm + i * 16 + lq * 4;
#pragma unroll
                for (int r = 0; r < 4; r++)
                    oq[(size_t)(rbase + r) * NE + col] = (_Float16)(acc[i][j][r] + bb);
            }
        }
    } else if (which == 1) {
#pragma unroll
        for (int j = 0; j < 4; j++) {
            const int col = n0 + wn + j * 16 + lcol;
            const int cch = col >> 3, clo = col & 7;
            const float bb = bias[col];
#pragma unroll
            for (int i = 0; i < 4; i++) {
                const int rbase = m0 + wm + i * 16 + lq * 4;
#pragma unroll
                for (int r = 0; r < 4; r++) {
                    const int s = rbase + r;
                    ok[(size_t)s * NE + ((cch ^ (s & 7)) << 3) + clo] =
                        (_Float16)(acc[i][j][r] + bb);
                }
            }
        }
    } else {
#pragma unroll
        for (int j = 0; j < 4; j++) {
            const int d = n0 + wn + j * 16 + lcol;
            const float bb = bias[d];
#pragma unroll
            for (int i = 0; i < 4; i++) {
                const int rbase = m0 + wm + i * 16 + lq * 4;
                const int bat = rbase >> 12;
                const int sl  = rbase & 4095;
                const int kc  = sl >> 6;
                const int slot = ((sl >> 3) & 7) ^ (d & 7);
                f16x4 pk;
#pragma unroll
                for (int r = 0; r < 4; r++) pk[r] = (_Float16)(acc[i][j][r] + bb);
                *(f16x4*)&ovt[(((size_t)bat * 64 + kc) * NE + d) * 64 + slot * 8 + (sl & 7)] = pk;
            }
        }
    }
}

// ---------------- Stage 2: flash attention v8 ---------------------------
// 512 thr = 8 waves; block owns 64 q-rows, full 4096 keys, KB=64/iter.
// Wave (rt=w&3, g=w>>2): 16 q-rows rt*16..; QK over ALL 64 keys (redundant
// across g-pair) -> softmax fully wave-local (no cross-wave exchange,
// no extra barriers). PV covers E-half g*256..+256.
// Split K/V staging pipeline: K_{t+1} issued after QK(t) frees Kb,
// V_{t+1} after PV(t) frees Vb; counted vmcnt(8), no drain in loop.
__global__ __launch_bounds__(512, 2) void attn_kernel(
    const _Float16* __restrict__ q, const _Float16* __restrict__ ksw,
    const _Float16* __restrict__ vsw, float* __restrict__ out, int b0)
{
    __shared__ __align__(16) _Float16 Kb[64 * 512];
    __shared__ __align__(16) _Float16 Vb[512 * 64];
    __shared__ __align__(16) _Float16 Pb[8][16 * 72];

    const int t = threadIdx.x, w = t >> 6, ln = t & 63;
    const int lcol = ln & 15, lq = ln >> 4;
    const int rt = w & 3, g = w >> 2;
    const int xm = lcol & 7;

    // XCD-aware swizzle (proven: FETCH 139->41 MB): 2 XCDs per batch
    int qx, rel;
    if (gridDim.y == 4) {
        const int id = blockIdx.x + (blockIdx.y << 6);   // 0..255, hw xcd = id&7
        const int xcd = id & 7, slot = id >> 3;          // slot 0..31
        rel = xcd >> 1;
        qx  = ((xcd & 1) << 5) + slot;
    } else { qx = blockIdx.x; rel = blockIdx.y; }
    const int babs = b0 + rel;
    const int q0 = qx * 64;

    const _Float16* qp = q + ((size_t)rel * NS + q0 + rt * 16 + lcol) * NE + lq * 8;
    f16x8 qf[16];
#pragma unroll
    for (int ks = 0; ks < 16; ks++) qf[ks] = *(const f16x8*)(qp + ks * 32);

    const _Float16* kbase = ksw + (size_t)rel * NS * NE;
    const _Float16* vbase = vsw + (size_t)rel * NS * NE;

    f32x4 oacc[16] = {};
    float m_st[4] = {-1e30f, -1e30f, -1e30f, -1e30f};
    float l_st[4] = {0.f, 0.f, 0.f, 0.f};

    auto stageK = [&](int kc) {
        const _Float16* src = kbase + (size_t)kc * 64 * NE;
#pragma unroll
        for (int i = 0; i < 8; i++) {
            const int blk = i * 8 + w;                   // 1 KB block index
            gload_lds16(src + (size_t)blk * 512 + ln * 8, (_Float16*)Kb + blk * 512);
        }
    };
    auto stageV = [&](int kc) {
        const _Float16* src = vbase + (size_t)kc * NE * 64;
#pragma unroll
        for (int i = 0; i < 8; i++) {
            const int blk = i * 8 + w;
            gload_lds16(src + (size_t)blk * 512 + ln * 8, (_Float16*)Vb + blk * 512);
        }
    };

    stageK(0);
    stageV(0);

    for (int kc = 0; kc < 64; kc++) {
        // wait own K_t (V_t's 8 loads stay in flight), then cross-wave sync
        asm volatile("s_waitcnt vmcnt(8)" ::: "memory");
        __builtin_amdgcn_s_barrier();
        asm volatile("" ::: "memory");

        // ---- QK^T: 16 q-rows x ALL 64 keys (4 chunks of 16), K=512
        f32x4 s0 = {}, s1 = {}, s2 = {}, s3 = {};
        __builtin_amdgcn_s_setprio(1);
#pragma unroll
        for (int ks = 0; ks < 16; ks++) {
            const int ch = ((ks * 4 + lq) ^ xm) * 8;
            f16x8 k0 = *(const f16x8*)&Kb[(lcol)      * 512 + ch];
            f16x8 k1 = *(const f16x8*)&Kb[(16 + lcol) * 512 + ch];
            f16x8 k2 = *(const f16x8*)&Kb[(32 + lcol) * 512 + ch];
            f16x8 k3 = *(const f16x8*)&Kb[(48 + lcol) * 512 + ch];
            s0 = __builtin_amdgcn_mfma_f32_16x16x32_f16(qf[ks], k0, s0, 0, 0, 0);
            s1 = __builtin_amdgcn_mfma_f32_16x16x32_f16(qf[ks], k1, s1, 0, 0, 0);
            s2 = __builtin_amdgcn_mfma_f32_16x16x32_f16(qf[ks], k2, s2, 0, 0, 0);
            s3 = __builtin_amdgcn_mfma_f32_16x16x32_f16(qf[ks], k3, s3, 0, 0, 0);
        }
        __builtin_amdgcn_s_setprio(0);

        asm volatile("" ::: "memory");
        __builtin_amdgcn_s_barrier();                    // all waves done with Kb
        asm volatile("" ::: "memory");
        if (kc + 1 < 64) stageK(kc + 1);                 // overlaps softmax + PV

        // ---- wave-local softmax (rows lq*4+r, keys c*16+lcol)
        float alpha[4];
        float p0[4], p1[4], p2[4], p3[4];
#pragma unroll
        for (int r = 0; r < 4; r++) {
            float mx = fmaxf(fmaxf(s0[r], s1[r]), fmaxf(s2[r], s3[r]));
#pragma unroll
            for (int msk = 8; msk; msk >>= 1) mx = fmaxf(mx, __shfl_xor(mx, msk, 64));
            const float mn = fmaxf(m_st[r], mx);
            alpha[r] = __expf(m_st[r] - mn);
            p0[r] = __expf(s0[r] - mn);
            p1[r] = __expf(s1[r] - mn);
            p2[r] = __expf(s2[r] - mn);
            p3[r] = __expf(s3[r] - mn);
            float ls = (p0[r] + p1[r]) + (p2[r] + p3[r]);
#pragma unroll
            for (int msk = 8; msk; msk >>= 1) ls += __shfl_xor(ls, msk, 64);
            l_st[r] = l_st[r] * alpha[r] + ls;
            m_st[r] = mn;
            const int row = lq * 4 + r;
            Pb[w][row * 72 +      lcol] = (_Float16)p0[r];
            Pb[w][row * 72 + 16 + lcol] = (_Float16)p1[r];
            Pb[w][row * 72 + 32 + lcol] = (_Float16)p2[r];
            Pb[w][row * 72 + 48 + lcol] = (_Float16)p3[r];
        }
        const bool allone = (alpha[0] == 1.f) & (alpha[1] == 1.f) &
                            (alpha[2] == 1.f) & (alpha[3] == 1.f);
        if (!__all(allone)) {
#pragma unroll
            for (int et = 0; et < 16; et++) {
                oacc[et][0] *= alpha[0]; oacc[et][1] *= alpha[1];
                oacc[et][2] *= alpha[2]; oacc[et][3] *= alpha[3];
            }
        }
        // own-wave P A-fragments (intra-wave LDS round-trip, no barrier)
        f16x8 pa0 = *(const f16x8*)&Pb[w][lcol * 72 +      lq * 8];
        f16x8 pa1 = *(const f16x8*)&Pb[w][lcol * 72 + 32 + lq * 8];

        // wait own V_t (K_{t+1}'s 8 loads stay in flight), sync
        if (kc + 1 < 64) { asm volatile("s_waitcnt vmcnt(8)" ::: "memory"); }
        else             { asm volatile("s_waitcnt vmcnt(0)" ::: "memory"); }
        __builtin_amdgcn_s_barrier();
        asm volatile("" ::: "memory");

        // ---- PV: rows rt*16..+16, E-cols g*256..+256, K=64
        __builtin_amdgcn_s_setprio(1);
#pragma unroll
        for (int et = 0; et < 16; et++) {
            const int e = g * 256 + et * 16 + lcol;
            f16x8 v0 = *(const f16x8*)&Vb[e * 64 + ((lq ^ xm) * 8)];
            f16x8 v1 = *(const f16x8*)&Vb[e * 64 + (((4 + lq) ^ xm) * 8)];
            oacc[et] = __builtin_amdgcn_mfma_f32_16x16x32_f16(pa0, v0, oacc[et], 0, 0, 0);
            oacc[et] = __builtin_amdgcn_mfma_f32_16x16x32_f16(pa1, v1, oacc[et], 0, 0, 0);
        }
        __builtin_amdgcn_s_setprio(0);

        if (kc + 1 < 64) {
            asm volatile("" ::: "memory");
            __builtin_amdgcn_s_barrier();                // all waves done with Vb
            asm volatile("" ::: "memory");
            stageV(kc + 1);                              // overlaps next QK
        }
    }

#pragma unroll
    for (int r = 0; r < 4; r++) {
        const float inv = 1.0f / l_st[r];
        const size_t ob = ((size_t)babs * NS + q0 + rt * 16 + lq * 4 + r) * NE + g * 256 + lcol;
#pragma unroll
        for (int et = 0; et < 16; et++)
            out[ob + et * 16] = oacc[et][r] * inv;
    }
}

extern "C" void kernel_launch(void* const* d_in, const int* in_sizes, int n_in,
                              void* d_out, int out_size, void* d_ws, size_t ws_size,
                              hipStream_t stream) {
    const float* query = (const float*)d_in[0];
    const float* key_  = (const float*)d_in[1];
    const float* value = (const float*)d_in[2];
    const float* Wq    = (const float*)d_in[3];
    const float* bq    = (const float*)d_in[4];
    const float* Wk    = (const float*)d_in[5];
    const float* bk    = (const float*)d_in[6];
    const float* Wv    = (const float*)d_in[7];
    const float* bv    = (const float*)d_in[8];

    const size_t per_batch = (size_t)3 * NS * NE * 2;   // q + k_sw + v_sw f16 = 12 MiB
    int nb_chunk = (int)(ws_size / per_batch);
    if (nb_chunk > NB) nb_chunk = NB;
    if (nb_chunk < 1)  nb_chunk = 1;

    _Float16* qh  = (_Float16*)d_ws;
    _Float16* kh  = qh + (size_t)nb_chunk * NS * NE;
    _Float16* vth = kh + (size_t)nb_chunk * NS * NE;

    for (int b0 = 0; b0 < NB; b0 += nb_chunk) {
        int nb = NB - b0 < nb_chunk ? NB - b0 : nb_chunk;
        proj_kernel<<<dim3(nb * 128, 3, 1), 256, 0, stream>>>(
            query, key_, value, Wq, Wk, Wv, bq, bk, bv, qh, kh, vth, b0);
        attn_kernel<<<dim3(NS / 64, nb, 1), 512, 0, stream>>>(
            qh, kh, vth, (float*)d_out, b0);
    }
}